// Round 16
// baseline (33.113 us; speedup 1.0000x reference)
//
#include <hip/hip_runtime.h>

#define B_ 4
#define C_ 64
#define H_ 128
#define W_ 128
#define LOG2E 1.44269504088896340736f

typedef float v2f __attribute__((ext_vector_type(2)));

__device__ __forceinline__ v2f exp2v(v2f x) {
    return (v2f){ __builtin_amdgcn_exp2f(x.x), __builtin_amdgcn_exp2f(x.y) };
}

// R7 body unchanged. Launch-shape experiment: 1024-thread blocks, 256 wgs
// (1 per CU, one (b,c) image per block) instead of 256-thread x 1024 wgs.
// Same total waves (4096), same 4 waves/SIMD (1024-thr block forces VGPR<=128,
// body measured 120 in R13), 4x fewer workgroups to dispatch.
template<int HALF>
__device__ __forceinline__ void sa_body(int x0, int y0,
    const float* __restrict__ f1p, const float* __restrict__ f2p,
    const float* __restrict__ relp, float* __restrict__ outp)
{
    float rel5[5];
    #pragma unroll
    for (int k = 0; k < 5; ++k) rel5[k] = relp[k];

    const float mL = (x0 > 0) ? 1.0f : 0.0f;
    const float mR = (x0 < W_ - 4) ? 1.0f : 0.0f;
    const int eM = (x0 >= 4) ? x0 - 4 : 0;
    const int eP = (x0 <= W_ - 8) ? x0 + 4 : W_ - 4;

    float w[5][8];   // rolling window: image row (y0 + s - 2) in slot s (mod 5)

    auto load_row = [&](int slot, int ky) {
        const int kycl = ky < 0 ? 0 : (ky > H_ - 1 ? H_ - 1 : ky);
        const float rv = ((unsigned)ky < (unsigned)H_) ? 1.0f : 0.0f;
        const float* rp = f2p + kycl * W_;
        const float4 qm = *(const float4*)(rp + eM);
        const float4 q0 = *(const float4*)(rp + x0);
        const float4 qp = *(const float4*)(rp + eP);
        const float mLr = mL * rv, mRr = mR * rv;
        w[slot][0] = qm.z * mLr; w[slot][1] = qm.w * mLr;
        w[slot][2] = q0.x * rv;  w[slot][3] = q0.y * rv;
        w[slot][4] = q0.z * rv;  w[slot][5] = q0.w * rv;
        w[slot][6] = qp.x * mRr; w[slot][7] = qp.y * mRr;
    };

    #pragma unroll
    for (int t = 0; t < 4; ++t) load_row(t, y0 + t - 2);

    #pragma unroll
    for (int r = 0; r < 4; ++r) {
        load_row((r + 4) % 5, y0 + r + 2);

        const float4 q4 = *(const float4*)(f1p + (y0 + r) * W_ + x0);
        const float qs[4] = {q4.x, q4.y, q4.z, q4.w};
        float res[4];

        #pragma unroll
        for (int xo = 0; xo < 4; ++xo) {
            const float q2 = qs[xo] * LOG2E;
            const v2f q2v = {q2, q2};

            float pr[5];
            #pragma unroll
            for (int k = 0; k < 5; ++k) pr[k] = q2 * rel5[k];
            const v2f prA = {pr[0], pr[1]};
            const v2f prB = {pr[2], pr[3]};
            const float prC = pr[4];

            v2f s0 = {0.f, 0.f}, s1 = {0.f, 0.f};
            v2f d0 = {0.f, 0.f}, d1 = {0.f, 0.f};
            float lv[5];

            #pragma unroll
            for (int i = 0; i < 5; ++i) {
                const float* W8 = w[(r + i) % 5];
                const v2f va = {W8[xo + 0], W8[xo + 1]};
                const v2f vb = {W8[xo + 2], W8[xo + 3]};
                const v2f pa = (HALF == 0) ? (v2f){pr[i], pr[i]} : prA;
                const v2f pb = (HALF == 0) ? (v2f){pr[i], pr[i]} : prB;
                const v2f p0 = exp2v(__builtin_elementwise_fma(va, q2v, pa));
                s0 += p0; d0 = __builtin_elementwise_fma(p0, va, d0);
                const v2f p1 = exp2v(__builtin_elementwise_fma(vb, q2v, pb));
                s1 += p1; d1 = __builtin_elementwise_fma(p1, vb, d1);
                lv[i] = W8[xo + 4];
            }
            {
                const v2f v = {lv[0], lv[1]};
                const v2f pp = (HALF == 0) ? (v2f){pr[0], pr[1]} : (v2f){prC, prC};
                const v2f p = exp2v(__builtin_elementwise_fma(v, q2v, pp));
                s0 += p; d0 = __builtin_elementwise_fma(p, v, d0);
            }
            {
                const v2f v = {lv[2], lv[3]};
                const v2f pp = (HALF == 0) ? (v2f){pr[2], pr[3]} : (v2f){prC, prC};
                const v2f p = exp2v(__builtin_elementwise_fma(v, q2v, pp));
                s1 += p; d1 = __builtin_elementwise_fma(p, v, d1);
            }
            float ss, ds;
            {
                const float pp = (HALF == 0) ? pr[4] : prC;
                const float p = __builtin_amdgcn_exp2f(__builtin_fmaf(q2, lv[4], pp));
                ss = p; ds = p * lv[4];
            }
            const v2f st = s0 + s1, dt = d0 + d1;
            res[xo] = (dt.x + dt.y + ds) * __builtin_amdgcn_rcpf(st.x + st.y + ss);
        }

        *(float4*)(outp + (y0 + r) * W_ + x0) = (float4){res[0], res[1], res[2], res[3]};
    }
}

__global__ __launch_bounds__(1024) void sa_kernel(
    const float* __restrict__ f1, const float* __restrict__ f2,
    const float* __restrict__ relh, const float* __restrict__ relw,
    float* __restrict__ out)
{
    const int tid = threadIdx.x;
    const int xq  = tid & 31;            // 32 x-quads = full width
    const int ys  = tid >> 5;            // 0..31: 32 y-strips of 4 rows = 128 rows
    const int bc  = blockIdx.x;          // one (b,c) image per block
    const int c   = bc & (C_ - 1);
    const int b   = bc >> 6;
    const int x0  = xq << 2;
    const int y0  = ys << 2;

    const size_t img = (size_t)(b * C_ + c) * (H_ * W_);
    const float* f1p = f1 + img;
    const float* f2p = f2 + img;

    const int c_out = (c & 7) * 8 + (c >> 3);   // einsum channel transpose
    float* outp = out + (size_t)(b * C_ + c_out) * (H_ * W_);

    if (c < C_ / 2) sa_body<0>(x0, y0, f1p, f2p, relh + c * 5, outp);
    else            sa_body<1>(x0, y0, f1p, f2p, relw + (c - C_ / 2) * 5, outp);
}

extern "C" void kernel_launch(void* const* d_in, const int* in_sizes, int n_in,
                              void* d_out, int out_size, void* d_ws, size_t ws_size,
                              hipStream_t stream) {
    const float* f1   = (const float*)d_in[0];
    const float* f2   = (const float*)d_in[1];
    const float* relh = (const float*)d_in[2];
    const float* relw = (const float*)d_in[3];
    float* out = (float*)d_out;

    sa_kernel<<<B_ * C_, 1024, 0, stream>>>(f1, f2, relh, relw, out);  // 256 wgs, 1/CU
}